// Round 1
// baseline (1688.900 us; speedup 1.0000x reference)
//
#include <hip/hip_runtime.h>
#include <math.h>

#define B_   4
#define S_   2048
#define H_   1024
#define NH   16
#define HD   64
#define T_   (B_ * S_)       // 8192 tokens
#define SCHUNK 8

// ---------------------------------------------------------------------------
// elu(x) + 1 + eps  (jax.nn.elu, alpha=1)
__device__ __forceinline__ float elu_k(float x) {
    return (x > 0.f ? x : (expf(x) - 1.f)) + 1.000001f;
}

// ---------------------------------------------------------------------------
// coeff = sum_m softmax(gate)[m] * (1 - sigmoid(decay[m]))
__global__ void coeff_kernel(const float* __restrict__ decay,
                             const float* __restrict__ gate,
                             float* __restrict__ coeff) {
    if (threadIdx.x == 0 && blockIdx.x == 0) {
        float g0 = gate[0], g1 = gate[1], g2 = gate[2];
        float mx = fmaxf(g0, fmaxf(g1, g2));
        float e0 = expf(g0 - mx), e1 = expf(g1 - mx), e2 = expf(g2 - mx);
        float inv = 1.f / (e0 + e1 + e2);
        float es[3] = {e0, e1, e2};
        const float* dp = decay;
        float c = 0.f;
        for (int m = 0; m < 3; m++) {
            float ds = 1.f / (1.f + expf(-dp[m]));
            c += es[m] * inv * (1.f - ds);
        }
        *coeff = c;
    }
}

// ---------------------------------------------------------------------------
// RoPE tables: cos/sin of s * base^(-2i/64), i in [0,32)
__global__ void rope_table_kernel(float* __restrict__ cosT,
                                  float* __restrict__ sinT) {
    int idx = blockIdx.x * blockDim.x + threadIdx.x;
    if (idx >= S_ * 32) return;
    int s = idx >> 5, i = idx & 31;
    float inv = powf(10000.f, -(2.f * (float)i) / 64.f);
    float f = (float)s * inv;
    cosT[idx] = cosf(f);
    sinT[idx] = sinf(f);
}

// ---------------------------------------------------------------------------
// C[M,N] = A[M,K] @ B[K,N] + bias[N]   (fp32 tiled, 64x64x16, 4x4/thread)
__global__ __launch_bounds__(256) void gemm_bias_kernel(
    const float* __restrict__ A, const float* __restrict__ Bm,
    const float* __restrict__ bias, float* __restrict__ C,
    int M, int N, int K) {
    __shared__ float As[16][65];
    __shared__ float Bs[16][65];
    const int tid = threadIdx.x;
    const int tx = tid & 15, ty = tid >> 4;
    const int bn = blockIdx.x * 64, bm = blockIdx.y * 64;
    float acc[4][4] = {};
    for (int k0 = 0; k0 < K; k0 += 16) {
#pragma unroll
        for (int i = 0; i < 4; i++) {
            int idx = tid + i * 256;
            int r = idx >> 4, c = idx & 15;
            As[c][r] = A[(size_t)(bm + r) * K + (k0 + c)];
        }
#pragma unroll
        for (int i = 0; i < 4; i++) {
            int idx = tid + i * 256;
            int r = idx >> 6, c = idx & 63;
            Bs[r][c] = Bm[(size_t)(k0 + r) * N + (bn + c)];
        }
        __syncthreads();
#pragma unroll
        for (int kk = 0; kk < 16; kk++) {
            float a[4], b[4];
#pragma unroll
            for (int i = 0; i < 4; i++) a[i] = As[kk][ty * 4 + i];
#pragma unroll
            for (int j = 0; j < 4; j++) b[j] = Bs[kk][tx * 4 + j];
#pragma unroll
            for (int i = 0; i < 4; i++)
#pragma unroll
                for (int j = 0; j < 4; j++)
                    acc[i][j] = fmaf(a[i], b[j], acc[i][j]);
        }
        __syncthreads();
    }
#pragma unroll
    for (int i = 0; i < 4; i++) {
        int r = bm + ty * 4 + i;
#pragma unroll
        for (int j = 0; j < 4; j++) {
            int c = bn + tx * 4 + j;
            C[(size_t)r * N + c] = acc[i][j] + bias[c];
        }
    }
}

// ---------------------------------------------------------------------------
// g[t] = sigmoid(hs[t,:] . Wg + bg)   one wave per token
__global__ __launch_bounds__(256) void gate_kernel(
    const float* __restrict__ hs, const float* __restrict__ Wg,
    const float* __restrict__ bg, float* __restrict__ g) {
    int w = (blockIdx.x * 256 + threadIdx.x) >> 6;
    int lane = threadIdx.x & 63;
    const float* row = hs + (size_t)w * H_;
    float s = 0.f;
    for (int i = lane; i < H_; i += 64) s = fmaf(row[i], Wg[i], s);
#pragma unroll
    for (int off = 32; off > 0; off >>= 1) s += __shfl_down(s, off);
    if (lane == 0) g[w] = 1.f / (1.f + expf(-(s + bg[0])));
}

// ---------------------------------------------------------------------------
// In-place: q <- (elu(rope(q))+1+eps)*0.125 ; k <- (elu(rope(k))+1+eps)*m ; v <- v*m
// One thread per (token, head, d<32) pair — handles d and d+32.
__global__ __launch_bounds__(256) void rope_elu_kernel(
    float* __restrict__ q, float* __restrict__ k, float* __restrict__ v,
    const float* __restrict__ mask,
    const float* __restrict__ cosT, const float* __restrict__ sinT) {
    int idx = blockIdx.x * 256 + threadIdx.x;   // T_*NH*32 total
    int d = idx & 31;
    int n = (idx >> 5) & 15;
    int t = idx >> 9;
    int s = t & (S_ - 1);
    float c = cosT[s * 32 + d];
    float sn = sinT[s * 32 + d];
    size_t base = (size_t)t * H_ + n * HD + d;
    float m = mask[t];
    float x1, x2, r1, r2;
    // q
    x1 = q[base]; x2 = q[base + 32];
    r1 = x1 * c - x2 * sn;
    r2 = x2 * c + x1 * sn;
    q[base]      = elu_k(r1) * 0.125f;
    q[base + 32] = elu_k(r2) * 0.125f;
    // k
    x1 = k[base]; x2 = k[base + 32];
    r1 = x1 * c - x2 * sn;
    r2 = x2 * c + x1 * sn;
    k[base]      = elu_k(r1) * m;
    k[base + 32] = elu_k(r2) * m;
    // v
    v[base]      *= m;
    v[base + 32] *= m;
}

// ---------------------------------------------------------------------------
// kv[b,n,i,j] = sum_s k[b,s,n,i]*v[b,s,n,j]; ksum[b,n,i] = sum_s k[b,s,n,i]
// grid (B*NH, SCHUNK); atomic finalize into zeroed buffers.
__global__ __launch_bounds__(256) void kv_kernel(
    const float* __restrict__ k, const float* __restrict__ v,
    float* __restrict__ kv, float* __restrict__ ksum) {
    int bn = blockIdx.x;              // b*16+n
    int b = bn >> 4, n = bn & 15;
    int s0 = blockIdx.y * (S_ / SCHUNK);
    int tid = threadIdx.x;
    int ti = tid >> 4, tj = tid & 15;
    __shared__ float ks[64], vs[64];
    float acc[4][4] = {};
    float ksacc = 0.f;
    for (int ss = 0; ss < S_ / SCHUNK; ss++) {
        int s = s0 + ss;
        size_t base = ((size_t)(b * S_ + s)) * H_ + n * HD;
        if (tid < 64)            ks[tid]      = k[base + tid];
        else if (tid < 128)      vs[tid - 64] = v[base + tid - 64];
        __syncthreads();
        float a[4], bb[4];
#pragma unroll
        for (int i = 0; i < 4; i++) a[i] = ks[ti * 4 + i];
#pragma unroll
        for (int j = 0; j < 4; j++) bb[j] = vs[tj * 4 + j];
#pragma unroll
        for (int i = 0; i < 4; i++)
#pragma unroll
            for (int j = 0; j < 4; j++)
                acc[i][j] = fmaf(a[i], bb[j], acc[i][j]);
        if (tid < 64) ksacc += ks[tid];
        __syncthreads();
    }
#pragma unroll
    for (int i = 0; i < 4; i++)
#pragma unroll
        for (int j = 0; j < 4; j++)
            atomicAdd(&kv[((size_t)bn * 64 + ti * 4 + i) * 64 + tj * 4 + j],
                      acc[i][j]);
    if (tid < 64) atomicAdd(&ksum[bn * 64 + tid], ksacc);
}

// ---------------------------------------------------------------------------
// combined[t, n*64+d] = num * (g/den + (1-g)*coeff)
// num = q[t,n,:] . kv[b,n,:,d]; den = q[t,n,:] . ksum[b,n,:] + eps
__global__ __launch_bounds__(256) void combine_kernel(
    const float* __restrict__ q, const float* __restrict__ kv,
    const float* __restrict__ ksum, const float* __restrict__ g,
    const float* __restrict__ coeffp, float* __restrict__ outc) {
    int t = blockIdx.x;
    int b = t >> 11;                  // t / S_
    __shared__ float qs[1024];
    __shared__ float dens[16];
    for (int i = threadIdx.x; i < 1024; i += 256)
        qs[i] = q[(size_t)t * H_ + i];
    __syncthreads();
    if (threadIdx.x < 16) {
        int n = threadIdx.x;
        const float* kp = ksum + (b * 16 + n) * 64;
        float dsum = 0.f;
        for (int i = 0; i < 64; i++) dsum += qs[n * 64 + i] * kp[i];
        dens[n] = dsum + 1e-6f;
    }
    __syncthreads();
    float coeff = *coeffp;
    float gv = g[t];
    int d = threadIdx.x & 63;
    int n0 = threadIdx.x >> 6;        // 0..3
#pragma unroll
    for (int nn = 0; nn < 4; nn++) {
        int n = n0 + nn * 4;
        const float* kvp = kv + (size_t)(b * 16 + n) * 4096;
        float num = 0.f;
#pragma unroll 8
        for (int i = 0; i < 64; i++)
            num = fmaf(qs[n * 64 + i], kvp[i * 64 + d], num);
        outc[(size_t)t * H_ + n * 64 + d] =
            num * (gv / dens[n] + (1.f - gv) * coeff);
    }
}

// ---------------------------------------------------------------------------
extern "C" void kernel_launch(void* const* d_in, const int* in_sizes, int n_in,
                              void* d_out, int out_size, void* d_ws, size_t ws_size,
                              hipStream_t stream) {
    const float* hs    = (const float*)d_in[0];
    const float* mask  = (const float*)d_in[1];
    const float* Wq    = (const float*)d_in[2];
    const float* bq    = (const float*)d_in[3];
    const float* Wk    = (const float*)d_in[4];
    const float* bk    = (const float*)d_in[5];
    const float* Wv    = (const float*)d_in[6];
    const float* bv    = (const float*)d_in[7];
    const float* Wo    = (const float*)d_in[8];
    const float* bo    = (const float*)d_in[9];
    const float* Wg    = (const float*)d_in[10];
    const float* bg    = (const float*)d_in[11];
    const float* decay = (const float*)d_in[12];
    const float* gate  = (const float*)d_in[13];
    float* out = (float*)d_out;

    const size_t TH = (size_t)T_ * H_;          // 8388608
    float* ws    = (float*)d_ws;
    float* qbuf  = ws;                          // TH
    float* kbuf  = qbuf + TH;                   // TH
    float* vbuf  = kbuf + TH;                   // TH (reused as 'combined')
    float* kvb   = vbuf + TH;                   // 64*64*64 = 262144
    float* ksum  = kvb + 262144;                // 4096
    float* gbuf  = ksum + 4096;                 // 8192
    float* coeff = gbuf + 8192;                 // 64 (padded)
    float* cosT  = coeff + 64;                  // S_*32 = 65536
    float* sinT  = cosT + (size_t)S_ * 32;      // 65536

    // zero kv + ksum (ws is re-poisoned each call)
    hipMemsetAsync(kvb, 0, (262144 + 4096) * sizeof(float), stream);

    coeff_kernel<<<1, 64, 0, stream>>>(decay, gate, coeff);
    rope_table_kernel<<<(S_ * 32 + 255) / 256, 256, 0, stream>>>(cosT, sinT);

    dim3 gg(H_ / 64, T_ / 64);   // (16, 128)
    gemm_bias_kernel<<<gg, 256, 0, stream>>>(hs, Wq, bq, qbuf, T_, H_, H_);
    gemm_bias_kernel<<<gg, 256, 0, stream>>>(hs, Wk, bk, kbuf, T_, H_, H_);
    gemm_bias_kernel<<<gg, 256, 0, stream>>>(hs, Wv, bv, vbuf, T_, H_, H_);

    gate_kernel<<<T_ / 4, 256, 0, stream>>>(hs, Wg, bg, gbuf);

    rope_elu_kernel<<<(T_ * NH * 32) / 256, 256, 0, stream>>>(
        qbuf, kbuf, vbuf, mask, cosT, sinT);

    dim3 kvg(B_ * NH, SCHUNK);
    kv_kernel<<<kvg, 256, 0, stream>>>(kbuf, vbuf, kvb, ksum);

    combine_kernel<<<T_, 256, 0, stream>>>(qbuf, kvb, ksum, gbuf, coeff, vbuf);

    gemm_bias_kernel<<<gg, 256, 0, stream>>>(vbuf, Wo, bo, out, T_, H_, H_);
}

// Round 2
// 467.424 us; speedup vs baseline: 3.6132x; 3.6132x over previous
//
#include <hip/hip_runtime.h>
#include <math.h>

#define B_   4
#define S_   2048
#define H_   1024
#define NH   16
#define HD   64
#define T_   (B_ * S_)       // 8192 tokens
#define SCHUNK 8

typedef unsigned short u16;
typedef __bf16 bf16x8 __attribute__((ext_vector_type(8)));
typedef float  f32x4  __attribute__((ext_vector_type(4)));

// ---------------------------------------------------------------------------
__device__ __forceinline__ float elu_k(float x) {
    return (x > 0.f ? x : (expf(x) - 1.f)) + 1.000001f;
}

__device__ __forceinline__ u16 f2bf(float x) {
    union { float f; unsigned int u; } v; v.f = x;
    unsigned int r = v.u + 0x7FFFu + ((v.u >> 16) & 1u);
    return (u16)(r >> 16);
}

// async global->LDS, 16 bytes per lane. l must be the WAVE-UNIFORM base;
// HW adds lane*16.
__device__ __forceinline__ void async_load16(const u16* g, u16* l) {
    __builtin_amdgcn_global_load_lds(
        (const __attribute__((address_space(1))) void*)g,
        (__attribute__((address_space(3))) void*)l,
        16, 0, 0);
}

// ---------------------------------------------------------------------------
// coeff = sum_m softmax(gate)[m] * (1 - sigmoid(decay[m]))
__global__ void coeff_kernel(const float* __restrict__ decay,
                             const float* __restrict__ gate,
                             float* __restrict__ coeff) {
    if (threadIdx.x == 0 && blockIdx.x == 0) {
        float g0 = gate[0], g1 = gate[1], g2 = gate[2];
        float mx = fmaxf(g0, fmaxf(g1, g2));
        float e0 = expf(g0 - mx), e1 = expf(g1 - mx), e2 = expf(g2 - mx);
        float inv = 1.f / (e0 + e1 + e2);
        float es[3] = {e0, e1, e2};
        float c = 0.f;
        for (int m = 0; m < 3; m++) {
            float ds = 1.f / (1.f + expf(-decay[m]));
            c += es[m] * inv * (1.f - ds);
        }
        *coeff = c;
    }
}

// ---------------------------------------------------------------------------
__global__ void rope_table_kernel(float* __restrict__ cosT,
                                  float* __restrict__ sinT) {
    int idx = blockIdx.x * blockDim.x + threadIdx.x;
    if (idx >= S_ * 32) return;
    int s = idx >> 5, i = idx & 31;
    float inv = powf(10000.f, -(2.f * (float)i) / 64.f);
    float f = (float)s * inv;
    cosT[idx] = cosf(f);
    sinT[idx] = sinf(f);
}

// ---------------------------------------------------------------------------
// fp32 -> bf16 (4 elems/thread)
__global__ __launch_bounds__(256) void cvt_bf16_kernel(
    const float* __restrict__ in, u16* __restrict__ out, int n4) {
    int i = blockIdx.x * 256 + threadIdx.x;
    if (i >= n4) return;
    float4 f = ((const float4*)in)[i];
    ushort4 u;
    u.x = f2bf(f.x); u.y = f2bf(f.y); u.z = f2bf(f.z); u.w = f2bf(f.w);
    ((ushort4*)out)[i] = u;
}

// ---------------------------------------------------------------------------
// Transpose+convert weights: Wt[w*1024 + n][k] = bf16(W_w[k][n])
// grid (ntile=16, ktile=16, w=4), 256 threads, 64x64 tile.
__global__ __launch_bounds__(256) void pack_w_kernel(
    const float* __restrict__ Wq, const float* __restrict__ Wk,
    const float* __restrict__ Wv, const float* __restrict__ Wo,
    u16* __restrict__ Wt) {
    __shared__ u16 tile[64][65];
    const float* W = (blockIdx.z == 0) ? Wq :
                     (blockIdx.z == 1) ? Wk :
                     (blockIdx.z == 2) ? Wv : Wo;
    int nt = blockIdx.x * 64, kt = blockIdx.y * 64;
    int tid = threadIdx.x;
#pragma unroll
    for (int it = 0; it < 16; it++) {
        int i = it * 256 + tid;
        int kr = i >> 6, nc = i & 63;
        tile[kr][nc] = f2bf(W[(size_t)(kt + kr) * H_ + nt + nc]);
    }
    __syncthreads();
    size_t wbase = (size_t)blockIdx.z * H_;
#pragma unroll
    for (int it = 0; it < 16; it++) {
        int i = it * 256 + tid;
        int nr = i >> 6, kc = i & 63;
        Wt[(wbase + nt + nr) * H_ + kt + kc] = tile[kc][nr];
    }
}

__global__ void pack_bias_kernel(const float* __restrict__ bq,
                                 const float* __restrict__ bk,
                                 const float* __restrict__ bv,
                                 float* __restrict__ bqkv) {
    int i = blockIdx.x * 256 + threadIdx.x;
    if (i >= 3072) return;
    bqkv[i] = (i < 1024) ? bq[i] : (i < 2048) ? bk[i - 1024] : bv[i - 2048];
}

// ---------------------------------------------------------------------------
// bf16 MFMA GEMM: C[M][N] = A[M][1024] @ Bt[N][1024]^T + bias[N]
// 128x128 block tile, 4 waves 2x2, each wave 64x64 via 4x4 mfma_16x16x32.
// m97 structure: global_load_lds(16B) staging, 2-barrier K-loop.
__global__ __launch_bounds__(256) void gemm_bf16_kernel(
    const u16* __restrict__ A, const u16* __restrict__ Bt,
    const float* __restrict__ bias, float* __restrict__ C, int N) {
    constexpr int K = 1024;
    __shared__ u16 Asl[128 * 32];   // [m][k]
    __shared__ u16 Bsl[128 * 32];   // [n][k]
    const int tid  = threadIdx.x;
    const int wave = tid >> 6, lane = tid & 63;
    const int wm = (wave & 1) * 64, wn = (wave >> 1) * 64;
    const int bm = blockIdx.y * 128, bn = blockIdx.x * 128;
    const int l15 = lane & 15, quad = lane >> 4;

    f32x4 acc[4][4];
#pragma unroll
    for (int i = 0; i < 4; i++)
#pragma unroll
        for (int j = 0; j < 4; j++) acc[i][j] = {0.f, 0.f, 0.f, 0.f};

    for (int k0 = 0; k0 < K; k0 += 32) {
        // ---- stage A,B tiles (each 128 rows x 32 bf16 = 512 x 16B chunks)
#pragma unroll
        for (int r = 0; r < 2; r++) {
            int i = r * 256 + wave * 64 + lane;          // chunk id
            async_load16(&A[(size_t)(bm + (i >> 2)) * K + k0 + (i & 3) * 8],
                         &Asl[(r * 256 + wave * 64) * 8]);
        }
#pragma unroll
        for (int r = 0; r < 2; r++) {
            int i = r * 256 + wave * 64 + lane;
            async_load16(&Bt[(size_t)(bn + (i >> 2)) * K + k0 + (i & 3) * 8],
                         &Bsl[(r * 256 + wave * 64) * 8]);
        }
        asm volatile("s_waitcnt vmcnt(0)" ::: "memory");
        __syncthreads();

        // ---- fragments + MFMA
        bf16x8 af[4], bfr[4];
#pragma unroll
        for (int mi = 0; mi < 4; mi++)
            af[mi] = *(const bf16x8*)&Asl[(wm + mi * 16 + l15) * 32 + quad * 8];
#pragma unroll
        for (int nj = 0; nj < 4; nj++)
            bfr[nj] = *(const bf16x8*)&Bsl[(wn + nj * 16 + l15) * 32 + quad * 8];
#pragma unroll
        for (int mi = 0; mi < 4; mi++)
#pragma unroll
            for (int nj = 0; nj < 4; nj++)
                acc[mi][nj] = __builtin_amdgcn_mfma_f32_16x16x32_bf16(
                    af[mi], bfr[nj], acc[mi][nj], 0, 0, 0);
        __syncthreads();
    }

    // ---- epilogue: C/D layout col=lane&15, row=quad*4+reg
#pragma unroll
    for (int mi = 0; mi < 4; mi++) {
#pragma unroll
        for (int nj = 0; nj < 4; nj++) {
            int col = bn + wn + nj * 16 + l15;
            float bcol = bias[col];
#pragma unroll
            for (int r = 0; r < 4; r++) {
                int row = bm + wm + mi * 16 + quad * 4 + r;
                C[(size_t)row * N + col] = acc[mi][nj][r] + bcol;
            }
        }
    }
}

// ---------------------------------------------------------------------------
// g[t] = sigmoid(hs[t,:] . Wg + bg)   one wave per token
__global__ __launch_bounds__(256) void gate_kernel(
    const float* __restrict__ hs, const float* __restrict__ Wg,
    const float* __restrict__ bg, float* __restrict__ g) {
    int w = (blockIdx.x * 256 + threadIdx.x) >> 6;
    int lane = threadIdx.x & 63;
    const float* row = hs + (size_t)w * H_;
    float s = 0.f;
    for (int i = lane; i < H_; i += 64) s = fmaf(row[i], Wg[i], s);
#pragma unroll
    for (int off = 32; off > 0; off >>= 1) s += __shfl_down(s, off);
    if (lane == 0) g[w] = 1.f / (1.f + expf(-(s + bg[0])));
}

// ---------------------------------------------------------------------------
// In-place on qkv[T][3072]: q (+0), k (+1024), v (+2048)
__global__ __launch_bounds__(256) void rope_elu_kernel(
    float* __restrict__ qkv, const float* __restrict__ mask,
    const float* __restrict__ cosT, const float* __restrict__ sinT) {
    int idx = blockIdx.x * 256 + threadIdx.x;   // T_*NH*32 total
    int d = idx & 31;
    int n = (idx >> 5) & 15;
    int t = idx >> 9;
    int s = t & (S_ - 1);
    float c  = cosT[s * 32 + d];
    float sn = sinT[s * 32 + d];
    size_t base = (size_t)t * 3072 + n * HD + d;
    float m = mask[t];
    float x1, x2, r1, r2;
    // q
    x1 = qkv[base]; x2 = qkv[base + 32];
    r1 = x1 * c - x2 * sn;
    r2 = x2 * c + x1 * sn;
    qkv[base]      = elu_k(r1) * 0.125f;
    qkv[base + 32] = elu_k(r2) * 0.125f;
    // k
    x1 = qkv[base + 1024]; x2 = qkv[base + 1056];
    r1 = x1 * c - x2 * sn;
    r2 = x2 * c + x1 * sn;
    qkv[base + 1024] = elu_k(r1) * m;
    qkv[base + 1056] = elu_k(r2) * m;
    // v
    qkv[base + 2048] *= m;
    qkv[base + 2080] *= m;
}

// ---------------------------------------------------------------------------
// kv[b,n,i,j] += sum_s k*v ; ksum[b,n,i] += sum_s k
__global__ __launch_bounds__(256) void kv_kernel(
    const float* __restrict__ qkv,
    float* __restrict__ kv, float* __restrict__ ksum) {
    int bn = blockIdx.x;              // b*16+n
    int b = bn >> 4, n = bn & 15;
    int s0 = blockIdx.y * (S_ / SCHUNK);
    int tid = threadIdx.x;
    int ti = tid >> 4, tj = tid & 15;
    __shared__ float ks[64], vs[64];
    float acc[4][4] = {};
    float ksacc = 0.f;
    for (int ss = 0; ss < S_ / SCHUNK; ss++) {
        int s = s0 + ss;
        size_t base = ((size_t)(b * S_ + s)) * 3072 + n * HD;
        if (tid < 64)            ks[tid]      = qkv[base + 1024 + tid];
        else if (tid < 128)      vs[tid - 64] = qkv[base + 2048 + tid - 64];
        __syncthreads();
        float a[4], bb[4];
#pragma unroll
        for (int i = 0; i < 4; i++) a[i] = ks[ti * 4 + i];
#pragma unroll
        for (int j = 0; j < 4; j++) bb[j] = vs[tj * 4 + j];
#pragma unroll
        for (int i = 0; i < 4; i++)
#pragma unroll
            for (int j = 0; j < 4; j++)
                acc[i][j] = fmaf(a[i], bb[j], acc[i][j]);
        if (tid < 64) ksacc += ks[tid];
        __syncthreads();
    }
#pragma unroll
    for (int i = 0; i < 4; i++)
#pragma unroll
        for (int j = 0; j < 4; j++)
            atomicAdd(&kv[((size_t)bn * 64 + ti * 4 + i) * 64 + tj * 4 + j],
                      acc[i][j]);
    if (tid < 64) atomicAdd(&ksum[bn * 64 + tid], ksacc);
}

// ---------------------------------------------------------------------------
// combined (bf16) = num * (g/den + (1-g)*coeff)
__global__ __launch_bounds__(256) void combine_kernel(
    const float* __restrict__ qkv, const float* __restrict__ kv,
    const float* __restrict__ ksum, const float* __restrict__ g,
    const float* __restrict__ coeffp, u16* __restrict__ cmb) {
    int t = blockIdx.x;
    int b = t >> 11;
    __shared__ float qs[1024];
    __shared__ float dens[16];
    for (int i = threadIdx.x; i < 1024; i += 256)
        qs[i] = qkv[(size_t)t * 3072 + i];
    __syncthreads();
    if (threadIdx.x < 16) {
        int n = threadIdx.x;
        const float* kp = ksum + (b * 16 + n) * 64;
        float dsum = 0.f;
        for (int i = 0; i < 64; i++) dsum += qs[n * 64 + i] * kp[i];
        dens[n] = dsum + 1e-6f;
    }
    __syncthreads();
    float coeff = *coeffp;
    float gv = g[t];
    int d = threadIdx.x & 63;
    int n0 = threadIdx.x >> 6;
#pragma unroll
    for (int nn = 0; nn < 4; nn++) {
        int n = n0 + nn * 4;
        const float* kvp = kv + (size_t)(b * 16 + n) * 4096;
        float num = 0.f;
#pragma unroll 8
        for (int i = 0; i < 64; i++)
            num = fmaf(qs[n * 64 + i], kvp[i * 64 + d], num);
        cmb[(size_t)t * H_ + n * 64 + d] =
            f2bf(num * (gv / dens[n] + (1.f - gv) * coeff));
    }
}

// ---------------------------------------------------------------------------
extern "C" void kernel_launch(void* const* d_in, const int* in_sizes, int n_in,
                              void* d_out, int out_size, void* d_ws, size_t ws_size,
                              hipStream_t stream) {
    const float* hs    = (const float*)d_in[0];
    const float* mask  = (const float*)d_in[1];
    const float* Wq    = (const float*)d_in[2];
    const float* bq    = (const float*)d_in[3];
    const float* Wk    = (const float*)d_in[4];
    const float* bk    = (const float*)d_in[5];
    const float* Wv    = (const float*)d_in[6];
    const float* bv    = (const float*)d_in[7];
    const float* Wo    = (const float*)d_in[8];
    const float* bo    = (const float*)d_in[9];
    const float* Wg    = (const float*)d_in[10];
    const float* bg    = (const float*)d_in[11];
    const float* decay = (const float*)d_in[12];
    const float* gate  = (const float*)d_in[13];
    float* out = (float*)d_out;

    // ---- workspace layout
    float* ws    = (float*)d_ws;
    float* qkv   = ws;                          // T*3072 fp32
    float* kvb   = qkv + (size_t)T_ * 3072;     // 262144
    float* ksum  = kvb + 262144;                // 4096
    float* gbuf  = ksum + 4096;                 // 8192
    float* coeff = gbuf + 8192;                 // 64
    float* cosT  = coeff + 64;                  // 65536
    float* sinT  = cosT + (size_t)S_ * 32;      // 65536
    float* bqkv  = sinT + (size_t)S_ * 32;      // 3072
    u16*   hsb   = (u16*)(bqkv + 3072);         // T*1024 bf16
    u16*   Wt    = hsb + (size_t)T_ * H_;       // 4096*1024 bf16 (QKV^T | Wo^T)
    u16*   WoT   = Wt + (size_t)3072 * H_;
    u16*   cmb   = Wt + (size_t)4096 * H_;      // T*1024 bf16

    hipMemsetAsync(kvb, 0, (262144 + 4096) * sizeof(float), stream);

    coeff_kernel<<<1, 64, 0, stream>>>(decay, gate, coeff);
    rope_table_kernel<<<(S_ * 32 + 255) / 256, 256, 0, stream>>>(cosT, sinT);
    cvt_bf16_kernel<<<(T_ * H_ / 4 + 255) / 256, 256, 0, stream>>>(
        hs, hsb, T_ * H_ / 4);
    pack_w_kernel<<<dim3(16, 16, 4), 256, 0, stream>>>(Wq, Wk, Wv, Wo, Wt);
    pack_bias_kernel<<<12, 256, 0, stream>>>(bq, bk, bv, bqkv);

    // QKV fused GEMM: [8192 x 3072] = hsb @ [Wq|Wk|Wv]
    gemm_bf16_kernel<<<dim3(3072 / 128, T_ / 128), 256, 0, stream>>>(
        hsb, Wt, bqkv, qkv, 3072);

    gate_kernel<<<T_ / 4, 256, 0, stream>>>(hs, Wg, bg, gbuf);

    rope_elu_kernel<<<(T_ * NH * 32) / 256, 256, 0, stream>>>(
        qkv, mask, cosT, sinT);

    kv_kernel<<<dim3(B_ * NH, SCHUNK), 256, 0, stream>>>(qkv, kvb, ksum);

    combine_kernel<<<T_, 256, 0, stream>>>(qkv, kvb, ksum, gbuf, coeff, cmb);

    // out = cmb @ Wo + bo
    gemm_bf16_kernel<<<dim3(H_ / 128, T_ / 128), 256, 0, stream>>>(
        cmb, WoT, bo, out, H_);
}

// Round 3
// 400.634 us; speedup vs baseline: 4.2156x; 1.1667x over previous
//
#include <hip/hip_runtime.h>
#include <math.h>

#define B_   4
#define S_   2048
#define H_   1024
#define NH   16
#define HD   64
#define T_   (B_ * S_)       // 8192 tokens
#define NCH  16              // kv S-chunks

typedef unsigned short u16;
typedef __bf16 bf16x8 __attribute__((ext_vector_type(8)));
typedef float  f32x4  __attribute__((ext_vector_type(4)));

// ---------------------------------------------------------------------------
__device__ __forceinline__ float elu_k(float x) {
    return (x > 0.f ? x : (expf(x) - 1.f)) + 1.000001f;
}

__device__ __forceinline__ u16 f2bf(float x) {
    union { float f; unsigned int u; } v; v.f = x;
    unsigned int r = v.u + 0x7FFFu + ((v.u >> 16) & 1u);
    return (u16)(r >> 16);
}

// async global->LDS, 16 bytes per lane. l must be the WAVE-UNIFORM base.
__device__ __forceinline__ void async_load16(const u16* g, u16* l) {
    __builtin_amdgcn_global_load_lds(
        (const __attribute__((address_space(1))) void*)g,
        (__attribute__((address_space(3))) void*)l,
        16, 0, 0);
}

// ---------------------------------------------------------------------------
__global__ void coeff_kernel(const float* __restrict__ decay,
                             const float* __restrict__ gate,
                             float* __restrict__ coeff) {
    if (threadIdx.x == 0 && blockIdx.x == 0) {
        float g0 = gate[0], g1 = gate[1], g2 = gate[2];
        float mx = fmaxf(g0, fmaxf(g1, g2));
        float e0 = expf(g0 - mx), e1 = expf(g1 - mx), e2 = expf(g2 - mx);
        float inv = 1.f / (e0 + e1 + e2);
        float es[3] = {e0, e1, e2};
        float c = 0.f;
        for (int m = 0; m < 3; m++) {
            float ds = 1.f / (1.f + expf(-decay[m]));
            c += es[m] * inv * (1.f - ds);
        }
        *coeff = c;
    }
}

// ---------------------------------------------------------------------------
__global__ void rope_table_kernel(float* __restrict__ cosT,
                                  float* __restrict__ sinT) {
    int idx = blockIdx.x * blockDim.x + threadIdx.x;
    if (idx >= S_ * 32) return;
    int s = idx >> 5, i = idx & 31;
    float inv = powf(10000.f, -(2.f * (float)i) / 64.f);
    float f = (float)s * inv;
    cosT[idx] = cosf(f);
    sinT[idx] = sinf(f);
}

// ---------------------------------------------------------------------------
__global__ __launch_bounds__(256) void cvt_bf16_kernel(
    const float* __restrict__ in, u16* __restrict__ out, int n4) {
    int i = blockIdx.x * 256 + threadIdx.x;
    if (i >= n4) return;
    float4 f = ((const float4*)in)[i];
    ushort4 u;
    u.x = f2bf(f.x); u.y = f2bf(f.y); u.z = f2bf(f.z); u.w = f2bf(f.w);
    ((ushort4*)out)[i] = u;
}

// ---------------------------------------------------------------------------
// Transpose+convert weights: Wt[w*1024 + n][k] = bf16(W_w[k][n])
__global__ __launch_bounds__(256) void pack_w_kernel(
    const float* __restrict__ Wq, const float* __restrict__ Wk,
    const float* __restrict__ Wv, const float* __restrict__ Wo,
    u16* __restrict__ Wt) {
    __shared__ u16 tile[64][65];
    const float* W = (blockIdx.z == 0) ? Wq :
                     (blockIdx.z == 1) ? Wk :
                     (blockIdx.z == 2) ? Wv : Wo;
    int nt = blockIdx.x * 64, kt = blockIdx.y * 64;
    int tid = threadIdx.x;
#pragma unroll
    for (int it = 0; it < 16; it++) {
        int i = it * 256 + tid;
        int kr = i >> 6, nc = i & 63;
        tile[kr][nc] = f2bf(W[(size_t)(kt + kr) * H_ + nt + nc]);
    }
    __syncthreads();
    size_t wbase = (size_t)blockIdx.z * H_;
#pragma unroll
    for (int it = 0; it < 16; it++) {
        int i = it * 256 + tid;
        int nr = i >> 6, kc = i & 63;
        Wt[(wbase + nt + nr) * H_ + kt + kc] = tile[kc][nr];
    }
}

__global__ void pack_bias_kernel(const float* __restrict__ bq,
                                 const float* __restrict__ bk,
                                 const float* __restrict__ bv,
                                 float* __restrict__ bqkv) {
    int i = blockIdx.x * 256 + threadIdx.x;
    if (i >= 3072) return;
    bqkv[i] = (i < 1024) ? bq[i] : (i < 2048) ? bk[i - 1024] : bv[i - 2048];
}

// ---------------------------------------------------------------------------
// bf16 MFMA GEMM (m97 structure): C[M][N] = A[M][1024] @ Bt[N][1024]^T + bias
__global__ __launch_bounds__(256) void gemm_bf16_kernel(
    const u16* __restrict__ A, const u16* __restrict__ Bt,
    const float* __restrict__ bias, float* __restrict__ C, int N) {
    constexpr int K = 1024;
    __shared__ u16 Asl[128 * 32];   // [m][k]
    __shared__ u16 Bsl[128 * 32];   // [n][k]
    const int tid  = threadIdx.x;
    const int wave = tid >> 6, lane = tid & 63;
    const int wm = (wave & 1) * 64, wn = (wave >> 1) * 64;
    const int bm = blockIdx.y * 128, bn = blockIdx.x * 128;
    const int l15 = lane & 15, quad = lane >> 4;

    f32x4 acc[4][4];
#pragma unroll
    for (int i = 0; i < 4; i++)
#pragma unroll
        for (int j = 0; j < 4; j++) acc[i][j] = {0.f, 0.f, 0.f, 0.f};

    for (int k0 = 0; k0 < K; k0 += 32) {
#pragma unroll
        for (int r = 0; r < 2; r++) {
            int i = r * 256 + wave * 64 + lane;
            async_load16(&A[(size_t)(bm + (i >> 2)) * K + k0 + (i & 3) * 8],
                         &Asl[(r * 256 + wave * 64) * 8]);
        }
#pragma unroll
        for (int r = 0; r < 2; r++) {
            int i = r * 256 + wave * 64 + lane;
            async_load16(&Bt[(size_t)(bn + (i >> 2)) * K + k0 + (i & 3) * 8],
                         &Bsl[(r * 256 + wave * 64) * 8]);
        }
        asm volatile("s_waitcnt vmcnt(0)" ::: "memory");
        __syncthreads();

        bf16x8 af[4], bfr[4];
#pragma unroll
        for (int mi = 0; mi < 4; mi++)
            af[mi] = *(const bf16x8*)&Asl[(wm + mi * 16 + l15) * 32 + quad * 8];
#pragma unroll
        for (int nj = 0; nj < 4; nj++)
            bfr[nj] = *(const bf16x8*)&Bsl[(wn + nj * 16 + l15) * 32 + quad * 8];
#pragma unroll
        for (int mi = 0; mi < 4; mi++)
#pragma unroll
            for (int nj = 0; nj < 4; nj++)
                acc[mi][nj] = __builtin_amdgcn_mfma_f32_16x16x32_bf16(
                    af[mi], bfr[nj], acc[mi][nj], 0, 0, 0);
        __syncthreads();
    }

#pragma unroll
    for (int mi = 0; mi < 4; mi++) {
#pragma unroll
        for (int nj = 0; nj < 4; nj++) {
            int col = bn + wn + nj * 16 + l15;
            float bcol = bias[col];
#pragma unroll
            for (int r = 0; r < 4; r++) {
                int row = bm + wm + mi * 16 + quad * 4 + r;
                C[(size_t)row * N + col] = acc[mi][nj][r] + bcol;
            }
        }
    }
}

// ---------------------------------------------------------------------------
__global__ __launch_bounds__(256) void gate_kernel(
    const float* __restrict__ hs, const float* __restrict__ Wg,
    const float* __restrict__ bg, float* __restrict__ g) {
    int w = (blockIdx.x * 256 + threadIdx.x) >> 6;
    int lane = threadIdx.x & 63;
    const float* row = hs + (size_t)w * H_;
    float s = 0.f;
    for (int i = lane; i < H_; i += 64) s = fmaf(row[i], Wg[i], s);
#pragma unroll
    for (int off = 32; off > 0; off >>= 1) s += __shfl_down(s, off);
    if (lane == 0) g[w] = 1.f / (1.f + expf(-(s + bg[0])));
}

// ---------------------------------------------------------------------------
// In-place on qkv[T][3072]
__global__ __launch_bounds__(256) void rope_elu_kernel(
    float* __restrict__ qkv, const float* __restrict__ mask,
    const float* __restrict__ cosT, const float* __restrict__ sinT) {
    int idx = blockIdx.x * 256 + threadIdx.x;   // T_*NH*32 total
    int d = idx & 31;
    int n = (idx >> 5) & 15;
    int t = idx >> 9;
    int s = t & (S_ - 1);
    float c  = cosT[s * 32 + d];
    float sn = sinT[s * 32 + d];
    size_t base = (size_t)t * 3072 + n * HD + d;
    float m = mask[t];
    float x1, x2, r1, r2;
    x1 = qkv[base]; x2 = qkv[base + 32];
    r1 = x1 * c - x2 * sn;
    r2 = x2 * c + x1 * sn;
    qkv[base]      = elu_k(r1) * 0.125f;
    qkv[base + 32] = elu_k(r2) * 0.125f;
    x1 = qkv[base + 1024]; x2 = qkv[base + 1056];
    r1 = x1 * c - x2 * sn;
    r2 = x2 * c + x1 * sn;
    qkv[base + 1024] = elu_k(r1) * m;
    qkv[base + 1056] = elu_k(r2) * m;
    qkv[base + 2048] *= m;
    qkv[base + 2080] *= m;
}

// ---------------------------------------------------------------------------
// kv partials: grid (64 bn, NCH). Stage 8 s-rows per barrier via float4,
// register 4x4 outer-product accum, partials to scratch (no atomics).
__global__ __launch_bounds__(256) void kv_part_kernel(
    const float* __restrict__ qkv,
    float* __restrict__ kvpart, float* __restrict__ kspart) {
    int bn = blockIdx.x;
    int b = bn >> 4, n = bn & 15;
    const int rows = S_ / NCH;              // 128
    int s0 = blockIdx.y * rows;
    int tid = threadIdx.x;
    int ti = tid >> 4, tj = tid & 15;
    __shared__ float ks[8][64], vs[8][64];
    float acc[4][4] = {};
    float ksacc = 0.f;
    for (int ss = 0; ss < rows; ss += 8) {
        if (tid < 128) {
            int rr = tid >> 4, c4 = tid & 15;
            *(float4*)&ks[rr][c4 * 4] = *(const float4*)
                &qkv[((size_t)(b * S_ + s0 + ss + rr)) * 3072 + 1024 + n * HD + c4 * 4];
        } else {
            int rr = (tid - 128) >> 4, c4 = (tid - 128) & 15;
            *(float4*)&vs[rr][c4 * 4] = *(const float4*)
                &qkv[((size_t)(b * S_ + s0 + ss + rr)) * 3072 + 2048 + n * HD + c4 * 4];
        }
        __syncthreads();
#pragma unroll
        for (int r = 0; r < 8; r++) {
            float a[4], bb[4];
#pragma unroll
            for (int i = 0; i < 4; i++) a[i] = ks[r][ti * 4 + i];
#pragma unroll
            for (int j = 0; j < 4; j++) bb[j] = vs[r][tj * 4 + j];
#pragma unroll
            for (int i = 0; i < 4; i++)
#pragma unroll
                for (int j = 0; j < 4; j++)
                    acc[i][j] = fmaf(a[i], bb[j], acc[i][j]);
        }
        if (tid < 64) {
#pragma unroll
            for (int r = 0; r < 8; r++) ksacc += ks[r][tid];
        }
        __syncthreads();
    }
    size_t obase = ((size_t)blockIdx.y * 64 + bn) * 4096;
#pragma unroll
    for (int i = 0; i < 4; i++)
#pragma unroll
        for (int j = 0; j < 4; j++)
            kvpart[obase + (size_t)(ti * 4 + i) * 64 + tj * 4 + j] = acc[i][j];
    if (tid < 64)
        kspart[((size_t)blockIdx.y * 64 + bn) * 64 + tid] = ksacc;
}

// sum NCH partials: out[i] = sum_c part[c*stride + i]
__global__ __launch_bounds__(256) void reduce_part_kernel(
    const float* __restrict__ part, float* __restrict__ out,
    int n, int stride) {
    int i = blockIdx.x * 256 + threadIdx.x;
    if (i >= n) return;
    float s = 0.f;
#pragma unroll
    for (int c = 0; c < NCH; c++) s += part[(size_t)c * stride + i];
    out[i] = s;
}

// ---------------------------------------------------------------------------
// combine: grid (64 bn, 16 token-chunks), block 256 = 4 waves.
// kv[b,n] staged in LDS once; each wave does 8 tokens per pass:
// one LDS kv read per (i,lane), q broadcast via __shfl.
__global__ __launch_bounds__(256) void combine_kernel(
    const float* __restrict__ qkv, const float* __restrict__ kvb,
    const float* __restrict__ ksum, const float* __restrict__ g,
    const float* __restrict__ coeffp, u16* __restrict__ cmb) {
    int bn = blockIdx.x;
    int b = bn >> 4, n = bn & 15;
    __shared__ float kvs[4096];
    __shared__ float ksl[64];
    for (int i = threadIdx.x; i < 1024; i += 256)
        ((float4*)kvs)[i] = ((const float4*)(kvb + (size_t)bn * 4096))[i];
    if (threadIdx.x < 64) ksl[threadIdx.x] = ksum[bn * 64 + threadIdx.x];
    __syncthreads();

    int wave = threadIdx.x >> 6, lane = threadIdx.x & 63;
    float ksv = ksl[lane];
    float coeff = *coeffp;
    int sbase = blockIdx.y * 128 + wave * 32;     // 32 tokens per wave

    for (int grp = 0; grp < 4; grp++) {
        int t0 = b * S_ + sbase + grp * 8;
        float qreg[8], numv[8], denv[8];
#pragma unroll
        for (int tt = 0; tt < 8; tt++)
            qreg[tt] = qkv[(size_t)(t0 + tt) * 3072 + n * HD + lane];
#pragma unroll
        for (int tt = 0; tt < 8; tt++) {
            float d = qreg[tt] * ksv;
#pragma unroll
            for (int off = 32; off > 0; off >>= 1) d += __shfl_xor(d, off);
            denv[tt] = d + 1e-6f;
            numv[tt] = 0.f;
        }
        for (int i = 0; i < 64; i++) {
            float kvrow = kvs[i * 64 + lane];
#pragma unroll
            for (int tt = 0; tt < 8; tt++)
                numv[tt] = fmaf(__shfl(qreg[tt], i), kvrow, numv[tt]);
        }
#pragma unroll
        for (int tt = 0; tt < 8; tt++) {
            float gv = g[t0 + tt];
            cmb[(size_t)(t0 + tt) * H_ + n * HD + lane] =
                f2bf(numv[tt] * (gv / denv[tt] + (1.f - gv) * coeff));
        }
    }
}

// ---------------------------------------------------------------------------
extern "C" void kernel_launch(void* const* d_in, const int* in_sizes, int n_in,
                              void* d_out, int out_size, void* d_ws, size_t ws_size,
                              hipStream_t stream) {
    const float* hs    = (const float*)d_in[0];
    const float* mask  = (const float*)d_in[1];
    const float* Wq    = (const float*)d_in[2];
    const float* bq    = (const float*)d_in[3];
    const float* Wk    = (const float*)d_in[4];
    const float* bk    = (const float*)d_in[5];
    const float* Wv    = (const float*)d_in[6];
    const float* bv    = (const float*)d_in[7];
    const float* Wo    = (const float*)d_in[8];
    const float* bo    = (const float*)d_in[9];
    const float* Wg    = (const float*)d_in[10];
    const float* bg    = (const float*)d_in[11];
    const float* decay = (const float*)d_in[12];
    const float* gate  = (const float*)d_in[13];
    float* out = (float*)d_out;

    // ---- workspace layout
    float* ws    = (float*)d_ws;
    float* qkv   = ws;                          // T*3072 fp32 (96 MB)
    float* kvb   = qkv + (size_t)T_ * 3072;     // 262144
    float* ksum  = kvb + 262144;                // 4096
    float* gbuf  = ksum + 4096;                 // 8192
    float* coeff = gbuf + 8192;                 // 64
    float* cosT  = coeff + 64;                  // 65536
    float* sinT  = cosT + (size_t)S_ * 32;      // 65536
    float* bqkv  = sinT + (size_t)S_ * 32;      // 3072
    u16*   hsb   = (u16*)(bqkv + 3072);         // T*1024 bf16 (16 MB)
    u16*   Wt    = hsb + (size_t)T_ * H_;       // 4096*1024 bf16
    u16*   WoT   = Wt + (size_t)3072 * H_;
    u16*   cmb   = Wt + (size_t)4096 * H_;      // T*1024 bf16
    float* kspart = (float*)(cmb + (size_t)T_ * H_);  // NCH*4096 (256 KB)
    // kvpart (16 MB) overlays hsb — hsb is dead after the QKV GEMM.
    float* kvpart = (float*)hsb;

    coeff_kernel<<<1, 64, 0, stream>>>(decay, gate, coeff);
    rope_table_kernel<<<(S_ * 32 + 255) / 256, 256, 0, stream>>>(cosT, sinT);
    cvt_bf16_kernel<<<(T_ * H_ / 4 + 255) / 256, 256, 0, stream>>>(
        hs, hsb, T_ * H_ / 4);
    pack_w_kernel<<<dim3(16, 16, 4), 256, 0, stream>>>(Wq, Wk, Wv, Wo, Wt);
    pack_bias_kernel<<<12, 256, 0, stream>>>(bq, bk, bv, bqkv);

    // QKV fused GEMM: [8192 x 3072] = hsb @ [Wq|Wk|Wv]
    gemm_bf16_kernel<<<dim3(3072 / 128, T_ / 128), 256, 0, stream>>>(
        hsb, Wt, bqkv, qkv, 3072);

    gate_kernel<<<T_ / 4, 256, 0, stream>>>(hs, Wg, bg, gbuf);

    rope_elu_kernel<<<(T_ * NH * 32) / 256, 256, 0, stream>>>(
        qkv, mask, cosT, sinT);

    kv_part_kernel<<<dim3(B_ * NH, NCH), 256, 0, stream>>>(
        qkv, kvpart, kspart);
    reduce_part_kernel<<<(262144 + 255) / 256, 256, 0, stream>>>(
        kvpart, kvb, 262144, 262144);
    reduce_part_kernel<<<(4096 + 255) / 256, 256, 0, stream>>>(
        kspart, ksum, 4096, 4096);

    combine_kernel<<<dim3(B_ * NH, 16), 256, 0, stream>>>(
        qkv, kvb, ksum, gbuf, coeff, cmb);

    // out = cmb @ Wo + bo
    gemm_bf16_kernel<<<dim3(H_ / 128, T_ / 128), 256, 0, stream>>>(
        cmb, WoT, bo, out, H_);
}

// Round 4
// 288.676 us; speedup vs baseline: 5.8505x; 1.3878x over previous
//
#include <hip/hip_runtime.h>
#include <math.h>

#define B_   4
#define S_   2048
#define H_   1024
#define NH   16
#define HD   64
#define T_   (B_ * S_)       // 8192 tokens
#define NCH  16              // kv S-chunks

typedef unsigned short u16;
typedef __bf16 bf16x8 __attribute__((ext_vector_type(8)));
typedef float  f32x4  __attribute__((ext_vector_type(4)));

// ---------------------------------------------------------------------------
__device__ __forceinline__ float elu_k(float x) {
    return (x > 0.f ? x : (expf(x) - 1.f)) + 1.000001f;
}

__device__ __forceinline__ u16 f2bf(float x) {
    union { float f; unsigned int u; } v; v.f = x;
    unsigned int r = v.u + 0x7FFFu + ((v.u >> 16) & 1u);
    return (u16)(r >> 16);
}

__device__ __forceinline__ float bfl(unsigned int u) {   // low bf16 -> f32
    union { unsigned int u; float f; } v; v.u = u << 16; return v.f;
}
__device__ __forceinline__ float bfh(unsigned int u) {   // high bf16 -> f32
    union { unsigned int u; float f; } v; v.u = u & 0xFFFF0000u; return v.f;
}

// async global->LDS, 16 bytes per lane; l is the WAVE-UNIFORM base.
__device__ __forceinline__ void async_load16(const u16* g, u16* l) {
    __builtin_amdgcn_global_load_lds(
        (const __attribute__((address_space(1))) void*)g,
        (__attribute__((address_space(3))) void*)l,
        16, 0, 0);
}

// ---------------------------------------------------------------------------
__global__ void coeff_kernel(const float* __restrict__ decay,
                             const float* __restrict__ gate,
                             float* __restrict__ coeff) {
    if (threadIdx.x == 0 && blockIdx.x == 0) {
        float g0 = gate[0], g1 = gate[1], g2 = gate[2];
        float mx = fmaxf(g0, fmaxf(g1, g2));
        float e0 = expf(g0 - mx), e1 = expf(g1 - mx), e2 = expf(g2 - mx);
        float inv = 1.f / (e0 + e1 + e2);
        float es[3] = {e0, e1, e2};
        float c = 0.f;
        for (int m = 0; m < 3; m++) {
            float ds = 1.f / (1.f + expf(-decay[m]));
            c += es[m] * inv * (1.f - ds);
        }
        *coeff = c;
    }
}

// ---------------------------------------------------------------------------
__global__ void rope_table_kernel(float* __restrict__ cosT,
                                  float* __restrict__ sinT) {
    int idx = blockIdx.x * blockDim.x + threadIdx.x;
    if (idx >= S_ * 32) return;
    int s = idx >> 5, i = idx & 31;
    float inv = powf(10000.f, -(2.f * (float)i) / 64.f);
    float f = (float)s * inv;
    cosT[idx] = cosf(f);
    sinT[idx] = sinf(f);
}

// ---------------------------------------------------------------------------
__global__ __launch_bounds__(256) void cvt_bf16_kernel(
    const float* __restrict__ in, u16* __restrict__ out, int n4) {
    int i = blockIdx.x * 256 + threadIdx.x;
    if (i >= n4) return;
    float4 f = ((const float4*)in)[i];
    ushort4 u;
    u.x = f2bf(f.x); u.y = f2bf(f.y); u.z = f2bf(f.z); u.w = f2bf(f.w);
    ((ushort4*)out)[i] = u;
}

// ---------------------------------------------------------------------------
// Transpose+convert weights: Wt[w*1024 + n][k] = bf16(W_w[k][n])
__global__ __launch_bounds__(256) void pack_w_kernel(
    const float* __restrict__ Wq, const float* __restrict__ Wk,
    const float* __restrict__ Wv, const float* __restrict__ Wo,
    u16* __restrict__ Wt) {
    __shared__ u16 tile[64][65];
    const float* W = (blockIdx.z == 0) ? Wq :
                     (blockIdx.z == 1) ? Wk :
                     (blockIdx.z == 2) ? Wv : Wo;
    int nt = blockIdx.x * 64, kt = blockIdx.y * 64;
    int tid = threadIdx.x;
#pragma unroll
    for (int it = 0; it < 16; it++) {
        int i = it * 256 + tid;
        int kr = i >> 6, nc = i & 63;
        tile[kr][nc] = f2bf(W[(size_t)(kt + kr) * H_ + nt + nc]);
    }
    __syncthreads();
    size_t wbase = (size_t)blockIdx.z * H_;
#pragma unroll
    for (int it = 0; it < 16; it++) {
        int i = it * 256 + tid;
        int nr = i >> 6, kc = i & 63;
        Wt[(wbase + nt + nr) * H_ + kt + kc] = tile[kc][nr];
    }
}

__global__ void pack_bias_kernel(const float* __restrict__ bq,
                                 const float* __restrict__ bk,
                                 const float* __restrict__ bv,
                                 float* __restrict__ bqkv) {
    int i = blockIdx.x * 256 + threadIdx.x;
    if (i >= 3072) return;
    bqkv[i] = (i < 1024) ? bq[i] : (i < 2048) ? bk[i - 1024] : bv[i - 2048];
}

// ---------------------------------------------------------------------------
// QKV GEMM with fused rope+elu+mask epilogue.
// A[8192][1024] bf16 @ Wt[3072][1024]^T + bias, then per-region transform,
// written bf16 head-major: qb/kb/vb[(b*16+n)*2048 + s][d].
// A wave's 64-col span == one head; rope pair (d, d+32) = acc cols (nj, nj+2).
__global__ __launch_bounds__(256) void gemm_qkv_kernel(
    const u16* __restrict__ A, const u16* __restrict__ Bt,
    const float* __restrict__ bias, const float* __restrict__ mask,
    const float* __restrict__ cosT, const float* __restrict__ sinT,
    u16* __restrict__ qb, u16* __restrict__ kb, u16* __restrict__ vb) {
    constexpr int K = 1024;
    __shared__ u16 Asl[128 * 32];
    __shared__ u16 Bsl[128 * 32];
    const int tid  = threadIdx.x;
    const int wave = tid >> 6, lane = tid & 63;
    const int wm = (wave & 1) * 64, wn = (wave >> 1) * 64;
    const int bm = blockIdx.y * 128, bn = blockIdx.x * 128;
    const int l15 = lane & 15, quad = lane >> 4;

    f32x4 acc[4][4];
#pragma unroll
    for (int i = 0; i < 4; i++)
#pragma unroll
        for (int j = 0; j < 4; j++) acc[i][j] = {0.f, 0.f, 0.f, 0.f};

    for (int k0 = 0; k0 < K; k0 += 32) {
#pragma unroll
        for (int r = 0; r < 2; r++) {
            int i = r * 256 + wave * 64 + lane;
            async_load16(&A[(size_t)(bm + (i >> 2)) * K + k0 + (i & 3) * 8],
                         &Asl[(r * 256 + wave * 64) * 8]);
        }
#pragma unroll
        for (int r = 0; r < 2; r++) {
            int i = r * 256 + wave * 64 + lane;
            async_load16(&Bt[(size_t)(bn + (i >> 2)) * K + k0 + (i & 3) * 8],
                         &Bsl[(r * 256 + wave * 64) * 8]);
        }
        asm volatile("s_waitcnt vmcnt(0)" ::: "memory");
        __syncthreads();

        bf16x8 af[4], bfr[4];
#pragma unroll
        for (int mi = 0; mi < 4; mi++)
            af[mi] = *(const bf16x8*)&Asl[(wm + mi * 16 + l15) * 32 + quad * 8];
#pragma unroll
        for (int nj = 0; nj < 4; nj++)
            bfr[nj] = *(const bf16x8*)&Bsl[(wn + nj * 16 + l15) * 32 + quad * 8];
#pragma unroll
        for (int mi = 0; mi < 4; mi++)
#pragma unroll
            for (int nj = 0; nj < 4; nj++)
                acc[mi][nj] = __builtin_amdgcn_mfma_f32_16x16x32_bf16(
                    af[mi], bfr[nj], acc[mi][nj], 0, 0, 0);
        __syncthreads();
    }

    // ---- fused epilogue
    const int colbase = bn + wn;              // multiple of 64
    const int region  = colbase >> 10;        // 0=q 1=k 2=v
    const int n       = (colbase & 1023) >> 6;
    float bc[4];
#pragma unroll
    for (int nj = 0; nj < 4; nj++) bc[nj] = bias[colbase + nj * 16 + l15];
    u16* outp = (region == 0) ? qb : (region == 1) ? kb : vb;

#pragma unroll
    for (int mi = 0; mi < 4; mi++) {
#pragma unroll
        for (int r = 0; r < 4; r++) {
            int row = bm + wm + mi * 16 + quad * 4 + r;
            int b = row >> 11, s = row & (S_ - 1);
            size_t obase = ((size_t)(b * 16 + n) * S_ + s) * 64;
            if (region < 2) {
                float mfac = (region == 0) ? 0.125f : mask[row];
#pragma unroll
                for (int p = 0; p < 2; p++) {
                    int d1 = p * 16 + l15;
                    float c  = cosT[s * 32 + d1];
                    float sn = sinT[s * 32 + d1];
                    float x1 = acc[mi][p][r]     + bc[p];
                    float x2 = acc[mi][p + 2][r] + bc[p + 2];
                    float r1 = x1 * c - x2 * sn;
                    float r2 = x2 * c + x1 * sn;
                    outp[obase + d1]      = f2bf(elu_k(r1) * mfac);
                    outp[obase + d1 + 32] = f2bf(elu_k(r2) * mfac);
                }
            } else {
                float mfac = mask[row];
#pragma unroll
                for (int nj = 0; nj < 4; nj++)
                    outp[obase + nj * 16 + l15] =
                        f2bf((acc[mi][nj][r] + bc[nj]) * mfac);
            }
        }
    }
}

// ---------------------------------------------------------------------------
// Plain bf16 GEMM for the output projection: C fp32 = A @ Bt^T + bias.
__global__ __launch_bounds__(256) void gemm_bf16_kernel(
    const u16* __restrict__ A, const u16* __restrict__ Bt,
    const float* __restrict__ bias, float* __restrict__ C, int N) {
    constexpr int K = 1024;
    __shared__ u16 Asl[128 * 32];
    __shared__ u16 Bsl[128 * 32];
    const int tid  = threadIdx.x;
    const int wave = tid >> 6, lane = tid & 63;
    const int wm = (wave & 1) * 64, wn = (wave >> 1) * 64;
    const int bm = blockIdx.y * 128, bn = blockIdx.x * 128;
    const int l15 = lane & 15, quad = lane >> 4;

    f32x4 acc[4][4];
#pragma unroll
    for (int i = 0; i < 4; i++)
#pragma unroll
        for (int j = 0; j < 4; j++) acc[i][j] = {0.f, 0.f, 0.f, 0.f};

    for (int k0 = 0; k0 < K; k0 += 32) {
#pragma unroll
        for (int r = 0; r < 2; r++) {
            int i = r * 256 + wave * 64 + lane;
            async_load16(&A[(size_t)(bm + (i >> 2)) * K + k0 + (i & 3) * 8],
                         &Asl[(r * 256 + wave * 64) * 8]);
        }
#pragma unroll
        for (int r = 0; r < 2; r++) {
            int i = r * 256 + wave * 64 + lane;
            async_load16(&Bt[(size_t)(bn + (i >> 2)) * K + k0 + (i & 3) * 8],
                         &Bsl[(r * 256 + wave * 64) * 8]);
        }
        asm volatile("s_waitcnt vmcnt(0)" ::: "memory");
        __syncthreads();

        bf16x8 af[4], bfr[4];
#pragma unroll
        for (int mi = 0; mi < 4; mi++)
            af[mi] = *(const bf16x8*)&Asl[(wm + mi * 16 + l15) * 32 + quad * 8];
#pragma unroll
        for (int nj = 0; nj < 4; nj++)
            bfr[nj] = *(const bf16x8*)&Bsl[(wn + nj * 16 + l15) * 32 + quad * 8];
#pragma unroll
        for (int mi = 0; mi < 4; mi++)
#pragma unroll
            for (int nj = 0; nj < 4; nj++)
                acc[mi][nj] = __builtin_amdgcn_mfma_f32_16x16x32_bf16(
                    af[mi], bfr[nj], acc[mi][nj], 0, 0, 0);
        __syncthreads();
    }

#pragma unroll
    for (int mi = 0; mi < 4; mi++) {
#pragma unroll
        for (int nj = 0; nj < 4; nj++) {
            int col = bn + wn + nj * 16 + l15;
            float bcol = bias[col];
#pragma unroll
            for (int r = 0; r < 4; r++) {
                int row = bm + wm + mi * 16 + quad * 4 + r;
                C[(size_t)row * N + col] = acc[mi][nj][r] + bcol;
            }
        }
    }
}

// ---------------------------------------------------------------------------
__global__ __launch_bounds__(256) void gate_kernel(
    const float* __restrict__ hs, const float* __restrict__ Wg,
    const float* __restrict__ bg, float* __restrict__ g) {
    int w = (blockIdx.x * 256 + threadIdx.x) >> 6;
    int lane = threadIdx.x & 63;
    const float* row = hs + (size_t)w * H_;
    float s = 0.f;
    for (int i = lane; i < H_; i += 64) s = fmaf(row[i], Wg[i], s);
#pragma unroll
    for (int off = 32; off > 0; off >>= 1) s += __shfl_down(s, off);
    if (lane == 0) g[w] = 1.f / (1.f + expf(-(s + bg[0])));
}

// ---------------------------------------------------------------------------
// kv partials from bf16 head-major k,v: grid (64 bn, NCH).
// 16 s-rows staged per barrier (bf16->fp32 in LDS), 4x4 register outer product.
__global__ __launch_bounds__(256) void kv_part_kernel(
    const u16* __restrict__ kb, const u16* __restrict__ vb,
    float* __restrict__ kvpart, float* __restrict__ kspart) {
    int bn = blockIdx.x;
    const int rows = S_ / NCH;              // 128
    int s0 = blockIdx.y * rows;
    int tid = threadIdx.x;
    int ti = tid >> 4, tj = tid & 15;
    __shared__ float ks[16][64], vs[16][64];
    float acc[4][4] = {};
    float ksacc = 0.f;
    const u16* kbase = kb + (size_t)bn * (S_ * 64) + (size_t)s0 * 64;
    const u16* vbase = vb + (size_t)bn * (S_ * 64) + (size_t)s0 * 64;
    for (int ss = 0; ss < rows; ss += 16) {
        {
            int half = tid >> 7;            // 0: k, 1: v
            int c = tid & 127;              // 128 chunks of 8 elems
            int rr = c >> 3, col = (c & 7) * 8;
            const u16* src = (half ? vbase : kbase) + (size_t)(ss + rr) * 64 + col;
            uint4 raw = *(const uint4*)src;
            float* dst = half ? &vs[rr][col] : &ks[rr][col];
            dst[0] = bfl(raw.x); dst[1] = bfh(raw.x);
            dst[2] = bfl(raw.y); dst[3] = bfh(raw.y);
            dst[4] = bfl(raw.z); dst[5] = bfh(raw.z);
            dst[6] = bfl(raw.w); dst[7] = bfh(raw.w);
        }
        __syncthreads();
#pragma unroll
        for (int r = 0; r < 16; r++) {
            float a[4], bb[4];
#pragma unroll
            for (int i = 0; i < 4; i++) a[i] = ks[r][ti * 4 + i];
#pragma unroll
            for (int j = 0; j < 4; j++) bb[j] = vs[r][tj * 4 + j];
#pragma unroll
            for (int i = 0; i < 4; i++)
#pragma unroll
                for (int j = 0; j < 4; j++)
                    acc[i][j] = fmaf(a[i], bb[j], acc[i][j]);
        }
        if (tid < 64) {
#pragma unroll
            for (int r = 0; r < 16; r++) ksacc += ks[r][tid];
        }
        __syncthreads();
    }
    size_t obase = ((size_t)blockIdx.y * 64 + bn) * 4096;
#pragma unroll
    for (int i = 0; i < 4; i++)
#pragma unroll
        for (int j = 0; j < 4; j++)
            kvpart[obase + (size_t)(ti * 4 + i) * 64 + tj * 4 + j] = acc[i][j];
    if (tid < 64)
        kspart[((size_t)blockIdx.y * 64 + bn) * 64 + tid] = ksacc;
}

// sum NCH partials
__global__ __launch_bounds__(256) void reduce_part_kernel(
    const float* __restrict__ part, float* __restrict__ out,
    int n, int stride) {
    int i = blockIdx.x * 256 + threadIdx.x;
    if (i >= n) return;
    float s = 0.f;
#pragma unroll
    for (int c = 0; c < NCH; c++) s += part[(size_t)c * stride + i];
    out[i] = s;
}

// ---------------------------------------------------------------------------
// MFMA combine: per (b,n), num = Q[256x64] @ kv[64x64], den via ksum-column
// MFMA. grid (64 bn, S_/256). Block 256 = 4 waves, each wave 64 tokens.
__global__ __launch_bounds__(256) void combine_kernel(
    const u16* __restrict__ qb, const float* __restrict__ kvb,
    const float* __restrict__ ksum, const float* __restrict__ g,
    const float* __restrict__ coeffp, u16* __restrict__ cmb) {
    int bn = blockIdx.x;
    int b = bn >> 4, n = bn & 15;
    __shared__ u16 qs[256 * 72];            // 36 KB, rows padded 64->72
    __shared__ u16 kvT[64 * 72];            // 9 KB: kvT[d][i] = kv[i][d]
    __shared__ u16 ksl[128];                // [0..63]=bf16 ksum, [64..127]=0
    int tid = threadIdx.x;
    int s0 = blockIdx.y * 256;

    const u16* qsrc = qb + (size_t)bn * (S_ * 64) + (size_t)s0 * 64;
    for (int c = tid; c < 2048; c += 256) {                 // 8 iters
        int t = c >> 3, k8 = (c & 7) * 8;
        float4 tmp = *(const float4*)(qsrc + (size_t)c * 8);
        *(float4*)&qs[t * 72 + k8] = tmp;
    }
    for (int c = tid; c < 1024; c += 256) {                 // 4 iters
        int i = c >> 4, d4 = (c & 15) * 4;
        float4 kvv = *(const float4*)&kvb[(size_t)bn * 4096 + i * 64 + d4];
        kvT[(d4 + 0) * 72 + i] = f2bf(kvv.x);
        kvT[(d4 + 1) * 72 + i] = f2bf(kvv.y);
        kvT[(d4 + 2) * 72 + i] = f2bf(kvv.z);
        kvT[(d4 + 3) * 72 + i] = f2bf(kvv.w);
    }
    if (tid < 64)        ksl[tid] = f2bf(ksum[bn * 64 + tid]);
    else if (tid < 128)  ksl[tid] = 0;
    __syncthreads();

    int wave = tid >> 6, lane = tid & 63;
    int l15 = lane & 15, quad = lane >> 4;
    int wt = wave * 64;

    int ko0 = (l15 == 0) ? quad * 8      : 64;   // zero rows at 64..127
    int ko1 = (l15 == 0) ? 32 + quad * 8 : 64;
    bf16x8 ksf0 = *(const bf16x8*)&ksl[ko0 & ~0u];
    bf16x8 ksf1 = *(const bf16x8*)&ksl[ko1];
    // (ksl[64..71] must be 16B-aligned zero — it is.)

    // B fragments for kv (hoisted)
    bf16x8 bfr0[4], bfr1[4];
#pragma unroll
    for (int nj = 0; nj < 4; nj++) {
        bfr0[nj] = *(const bf16x8*)&kvT[(nj * 16 + l15) * 72 + quad * 8];
        bfr1[nj] = *(const bf16x8*)&kvT[(nj * 16 + l15) * 72 + 32 + quad * 8];
    }

    f32x4 acc[4][4], dacc[4];
#pragma unroll
    for (int i = 0; i < 4; i++) {
        dacc[i] = {0.f, 0.f, 0.f, 0.f};
#pragma unroll
        for (int j = 0; j < 4; j++) acc[i][j] = {0.f, 0.f, 0.f, 0.f};
    }

#pragma unroll
    for (int mi = 0; mi < 4; mi++) {
        bf16x8 a0 = *(const bf16x8*)&qs[(wt + mi * 16 + l15) * 72 + quad * 8];
        bf16x8 a1 = *(const bf16x8*)&qs[(wt + mi * 16 + l15) * 72 + 32 + quad * 8];
        dacc[mi] = __builtin_amdgcn_mfma_f32_16x16x32_bf16(a0, ksf0, dacc[mi], 0, 0, 0);
        dacc[mi] = __builtin_amdgcn_mfma_f32_16x16x32_bf16(a1, ksf1, dacc[mi], 0, 0, 0);
#pragma unroll
        for (int nj = 0; nj < 4; nj++) {
            acc[mi][nj] = __builtin_amdgcn_mfma_f32_16x16x32_bf16(
                a0, bfr0[nj], acc[mi][nj], 0, 0, 0);
            acc[mi][nj] = __builtin_amdgcn_mfma_f32_16x16x32_bf16(
                a1, bfr1[nj], acc[mi][nj], 0, 0, 0);
        }
    }

    float coeff = *coeffp;
#pragma unroll
    for (int mi = 0; mi < 4; mi++) {
#pragma unroll
        for (int r = 0; r < 4; r++) {
            int s = s0 + wt + mi * 16 + quad * 4 + r;
            int t = b * S_ + s;
            float den = __shfl(dacc[mi][r], lane & 48) + 1e-6f;
            float gv = g[t];
            float w1 = gv / den + (1.f - gv) * coeff;
#pragma unroll
            for (int nj = 0; nj < 4; nj++) {
                int d = nj * 16 + l15;
                cmb[(size_t)t * H_ + n * 64 + d] = f2bf(acc[mi][nj][r] * w1);
            }
        }
    }
}

// ---------------------------------------------------------------------------
extern "C" void kernel_launch(void* const* d_in, const int* in_sizes, int n_in,
                              void* d_out, int out_size, void* d_ws, size_t ws_size,
                              hipStream_t stream) {
    const float* hs    = (const float*)d_in[0];
    const float* mask  = (const float*)d_in[1];
    const float* Wq    = (const float*)d_in[2];
    const float* bq    = (const float*)d_in[3];
    const float* Wk    = (const float*)d_in[4];
    const float* bk    = (const float*)d_in[5];
    const float* Wv    = (const float*)d_in[6];
    const float* bv    = (const float*)d_in[7];
    const float* Wo    = (const float*)d_in[8];
    const float* bo    = (const float*)d_in[9];
    const float* Wg    = (const float*)d_in[10];
    const float* bg    = (const float*)d_in[11];
    const float* decay = (const float*)d_in[12];
    const float* gate  = (const float*)d_in[13];
    float* out = (float*)d_out;

    // ---- workspace layout
    float* ws     = (float*)d_ws;
    float* kvb    = ws;                         // 262144
    float* ksum   = kvb + 262144;               // 4096
    float* gbuf   = ksum + 4096;                // 8192
    float* coeff  = gbuf + 8192;                // 64
    float* cosT   = coeff + 64;                 // 65536
    float* sinT   = cosT + 65536;               // 65536
    float* bqkv   = sinT + 65536;               // 3072 (+pad to 4096)
    float* kspart = bqkv + 4096;                // NCH*4096 = 65536
    float* kvpart = kspart + 65536;             // NCH*262144 = 4194304
    u16*   hsb    = (u16*)(kvpart + 4194304);   // T*1024
    u16*   Wt     = hsb + (size_t)T_ * H_;      // 4096*1024
    u16*   WoT    = Wt + (size_t)3072 * H_;
    u16*   qb     = Wt + (size_t)4096 * H_;     // T*1024 head-major
    u16*   kb     = qb + (size_t)T_ * H_;
    u16*   vb     = kb + (size_t)T_ * H_;
    u16*   cmb    = vb + (size_t)T_ * H_;

    coeff_kernel<<<1, 64, 0, stream>>>(decay, gate, coeff);
    rope_table_kernel<<<(S_ * 32 + 255) / 256, 256, 0, stream>>>(cosT, sinT);
    cvt_bf16_kernel<<<(T_ * H_ / 4 + 255) / 256, 256, 0, stream>>>(
        hs, hsb, T_ * H_ / 4);
    pack_w_kernel<<<dim3(16, 16, 4), 256, 0, stream>>>(Wq, Wk, Wv, Wo, Wt);
    pack_bias_kernel<<<12, 256, 0, stream>>>(bq, bk, bv, bqkv);

    gemm_qkv_kernel<<<dim3(3072 / 128, T_ / 128), 256, 0, stream>>>(
        hsb, Wt, bqkv, mask, cosT, sinT, qb, kb, vb);

    gate_kernel<<<T_ / 4, 256, 0, stream>>>(hs, Wg, bg, gbuf);

    kv_part_kernel<<<dim3(B_ * NH, NCH), 256, 0, stream>>>(
        kb, vb, kvpart, kspart);
    reduce_part_kernel<<<(262144 + 255) / 256, 256, 0, stream>>>(
        kvpart, kvb, 262144, 262144);
    reduce_part_kernel<<<(4096 + 255) / 256, 256, 0, stream>>>(
        kspart, ksum, 4096, 4096);

    combine_kernel<<<dim3(B_ * NH, S_ / 256), 256, 0, stream>>>(
        qb, kvb, ksum, gbuf, coeff, cmb);

    gemm_bf16_kernel<<<dim3(H_ / 128, T_ / 128), 256, 0, stream>>>(
        cmb, WoT, bo, out, H_);
}

// Round 5
// 272.532 us; speedup vs baseline: 6.1971x; 1.0592x over previous
//
#include <hip/hip_runtime.h>
#include <math.h>

#define B_   4
#define S_   2048
#define H_   1024
#define NH   16
#define HD   64
#define T_   (B_ * S_)       // 8192 tokens
#define NCH  16              // kv S-chunks

typedef unsigned short u16;
typedef __bf16 bf16x8 __attribute__((ext_vector_type(8)));
typedef float  f32x4  __attribute__((ext_vector_type(4)));

// ---------------------------------------------------------------------------
__device__ __forceinline__ float elu_k(float x) {
    return (x > 0.f ? x : (expf(x) - 1.f)) + 1.000001f;
}

__device__ __forceinline__ u16 f2bf(float x) {
    union { float f; unsigned int u; } v; v.f = x;
    unsigned int r = v.u + 0x7FFFu + ((v.u >> 16) & 1u);
    return (u16)(r >> 16);
}

__device__ __forceinline__ float bfl(unsigned int u) {
    union { unsigned int u; float f; } v; v.u = u << 16; return v.f;
}
__device__ __forceinline__ float bfh(unsigned int u) {
    union { unsigned int u; float f; } v; v.u = u & 0xFFFF0000u; return v.f;
}

// async global->LDS, 16 B/lane; LDS side is wave-uniform base + lane*16,
// global side is per-lane.
__device__ __forceinline__ void async_load16(const u16* g, u16* l) {
    __builtin_amdgcn_global_load_lds(
        (const __attribute__((address_space(1))) void*)g,
        (__attribute__((address_space(3))) void*)l,
        16, 0, 0);
}

// ---------------------------------------------------------------------------
// prep: rope tables + packed bias + coeff, one launch.
__global__ __launch_bounds__(256) void prep_kernel(
    const float* __restrict__ decay, const float* __restrict__ gate,
    float* __restrict__ coeff, float* __restrict__ cosT,
    float* __restrict__ sinT, const float* __restrict__ bq,
    const float* __restrict__ bk, const float* __restrict__ bv,
    float* __restrict__ bqkv) {
    int idx = blockIdx.x * 256 + threadIdx.x;
    if (idx < S_ * 32) {
        int s = idx >> 5, i = idx & 31;
        float inv = powf(10000.f, -(2.f * (float)i) / 64.f);
        float f = (float)s * inv;
        cosT[idx] = cosf(f);
        sinT[idx] = sinf(f);
    } else if (idx < S_ * 32 + 3072) {
        int i = idx - S_ * 32;
        bqkv[i] = (i < 1024) ? bq[i] : (i < 2048) ? bk[i - 1024] : bv[i - 2048];
    } else if (idx == S_ * 32 + 3072) {
        float g0 = gate[0], g1 = gate[1], g2 = gate[2];
        float mx = fmaxf(g0, fmaxf(g1, g2));
        float e0 = expf(g0 - mx), e1 = expf(g1 - mx), e2 = expf(g2 - mx);
        float inv = 1.f / (e0 + e1 + e2);
        float es[3] = {e0, e1, e2};
        float c = 0.f;
        for (int m = 0; m < 3; m++) {
            float ds = 1.f / (1.f + expf(-decay[m]));
            c += es[m] * inv * (1.f - ds);
        }
        *coeff = c;
    }
}

// ---------------------------------------------------------------------------
// Fused hs->bf16 convert + gate gemv. One block per token.
__global__ __launch_bounds__(256) void cvt_gate_kernel(
    const float* __restrict__ hs, const float* __restrict__ Wg,
    const float* __restrict__ bg, u16* __restrict__ hsb,
    float* __restrict__ gbuf) {
    int t = blockIdx.x;
    int i = threadIdx.x;
    float4 f = ((const float4*)(hs + (size_t)t * H_))[i];
    float4 w = ((const float4*)Wg)[i];
    ushort4 u;
    u.x = f2bf(f.x); u.y = f2bf(f.y); u.z = f2bf(f.z); u.w = f2bf(f.w);
    ((ushort4*)(hsb + (size_t)t * H_))[i] = u;
    float s = f.x * w.x + f.y * w.y + f.z * w.z + f.w * w.w;
#pragma unroll
    for (int off = 32; off > 0; off >>= 1) s += __shfl_down(s, off);
    __shared__ float wsum[4];
    if ((i & 63) == 0) wsum[i >> 6] = s;
    __syncthreads();
    if (i == 0) {
        float tot = wsum[0] + wsum[1] + wsum[2] + wsum[3];
        gbuf[t] = 1.f / (1.f + expf(-(tot + bg[0])));
    }
}

// ---------------------------------------------------------------------------
// Transpose+convert weights: Wt[w*1024 + n][k] = bf16(W_w[k][n])
__global__ __launch_bounds__(256) void pack_w_kernel(
    const float* __restrict__ Wq, const float* __restrict__ Wk,
    const float* __restrict__ Wv, const float* __restrict__ Wo,
    u16* __restrict__ Wt) {
    __shared__ u16 tile[64][65];
    const float* W = (blockIdx.z == 0) ? Wq :
                     (blockIdx.z == 1) ? Wk :
                     (blockIdx.z == 2) ? Wv : Wo;
    int nt = blockIdx.x * 64, kt = blockIdx.y * 64;
    int tid = threadIdx.x;
#pragma unroll
    for (int it = 0; it < 16; it++) {
        int i = it * 256 + tid;
        int kr = i >> 6, nc = i & 63;
        tile[kr][nc] = f2bf(W[(size_t)(kt + kr) * H_ + nt + nc]);
    }
    __syncthreads();
    size_t wbase = (size_t)blockIdx.z * H_;
#pragma unroll
    for (int it = 0; it < 16; it++) {
        int i = it * 256 + tid;
        int nr = i >> 6, kc = i & 63;
        Wt[(wbase + nt + nr) * H_ + kt + kc] = tile[kc][nr];
    }
}

// ---------------------------------------------------------------------------
// Shared GEMM K-loop body: BK=64 staged as two BK=32 half-tiles, each in the
// m97 bank-clean layout (row stride 32 u16). 8 async insts/lane/iter,
// 32 MFMAs/iter, 16 iterations.
#define GEMM_KLOOP(A_, Bt_, bm_, bn_)                                         \
    for (int k0 = 0; k0 < K; k0 += 64) {                                      \
        _Pragma("unroll")                                                     \
        for (int h = 0; h < 2; h++) {                                         \
            _Pragma("unroll")                                                 \
            for (int i = 0; i < 2; i++) {                                     \
                int r0 = (wave * 2 + i) * 16;                                 \
                int rr = lane >> 2, cc = lane & 3;                            \
                async_load16(&A_[(size_t)(bm_ + r0 + rr) * K + k0 + h * 32 + cc * 8], \
                             &Asl[h][r0 * 32]);                               \
                async_load16(&Bt_[(size_t)(bn_ + r0 + rr) * K + k0 + h * 32 + cc * 8], \
                             &Bsl[h][r0 * 32]);                               \
            }                                                                 \
        }                                                                     \
        asm volatile("s_waitcnt vmcnt(0)" ::: "memory");                      \
        __syncthreads();                                                      \
        _Pragma("unroll")                                                     \
        for (int h = 0; h < 2; h++) {                                         \
            bf16x8 af[4], bfr[4];                                             \
            _Pragma("unroll")                                                 \
            for (int mi = 0; mi < 4; mi++)                                    \
                af[mi] = *(const bf16x8*)&Asl[h][(wm + mi * 16 + l15) * 32 + quad * 8]; \
            _Pragma("unroll")                                                 \
            for (int nj = 0; nj < 4; nj++)                                    \
                bfr[nj] = *(const bf16x8*)&Bsl[h][(wn + nj * 16 + l15) * 32 + quad * 8]; \
            _Pragma("unroll")                                                 \
            for (int mi = 0; mi < 4; mi++)                                    \
                _Pragma("unroll")                                             \
                for (int nj = 0; nj < 4; nj++)                                \
                    acc[mi][nj] = __builtin_amdgcn_mfma_f32_16x16x32_bf16(    \
                        af[mi], bfr[nj], acc[mi][nj], 0, 0, 0);               \
        }                                                                     \
        __syncthreads();                                                      \
    }

// ---------------------------------------------------------------------------
// QKV GEMM with fused rope+elu+mask epilogue -> bf16 head-major qb/kb/vb.
__global__ __launch_bounds__(256) void gemm_qkv_kernel(
    const u16* __restrict__ A, const u16* __restrict__ Bt,
    const float* __restrict__ bias, const float* __restrict__ mask,
    const float* __restrict__ cosT, const float* __restrict__ sinT,
    u16* __restrict__ qb, u16* __restrict__ kb, u16* __restrict__ vb) {
    constexpr int K = 1024;
    __shared__ u16 Asl[2][128 * 32];
    __shared__ u16 Bsl[2][128 * 32];
    const int tid  = threadIdx.x;
    const int wave = tid >> 6, lane = tid & 63;
    const int wm = (wave & 1) * 64, wn = (wave >> 1) * 64;
    const int bm = blockIdx.y * 128, bn = blockIdx.x * 128;
    const int l15 = lane & 15, quad = lane >> 4;

    f32x4 acc[4][4];
#pragma unroll
    for (int i = 0; i < 4; i++)
#pragma unroll
        for (int j = 0; j < 4; j++) acc[i][j] = {0.f, 0.f, 0.f, 0.f};

    GEMM_KLOOP(A, Bt, bm, bn)

    // ---- fused epilogue
    const int colbase = bn + wn;              // multiple of 64
    const int region  = colbase >> 10;        // 0=q 1=k 2=v
    const int n       = (colbase & 1023) >> 6;
    float bc[4];
#pragma unroll
    for (int nj = 0; nj < 4; nj++) bc[nj] = bias[colbase + nj * 16 + l15];
    u16* outp = (region == 0) ? qb : (region == 1) ? kb : vb;

#pragma unroll
    for (int mi = 0; mi < 4; mi++) {
#pragma unroll
        for (int r = 0; r < 4; r++) {
            int row = bm + wm + mi * 16 + quad * 4 + r;
            int b = row >> 11, s = row & (S_ - 1);
            size_t obase = ((size_t)(b * 16 + n) * S_ + s) * 64;
            if (region < 2) {
                float mfac = (region == 0) ? 0.125f : mask[row];
#pragma unroll
                for (int p = 0; p < 2; p++) {
                    int d1 = p * 16 + l15;
                    float c  = cosT[s * 32 + d1];
                    float sn = sinT[s * 32 + d1];
                    float x1 = acc[mi][p][r]     + bc[p];
                    float x2 = acc[mi][p + 2][r] + bc[p + 2];
                    float r1 = x1 * c - x2 * sn;
                    float r2 = x2 * c + x1 * sn;
                    outp[obase + d1]      = f2bf(elu_k(r1) * mfac);
                    outp[obase + d1 + 32] = f2bf(elu_k(r2) * mfac);
                }
            } else {
                float mfac = mask[row];
#pragma unroll
                for (int nj = 0; nj < 4; nj++)
                    outp[obase + nj * 16 + l15] =
                        f2bf((acc[mi][nj][r] + bc[nj]) * mfac);
            }
        }
    }
}

// ---------------------------------------------------------------------------
// Output projection GEMM: C fp32 = A @ Bt^T + bias.
__global__ __launch_bounds__(256) void gemm_out_kernel(
    const u16* __restrict__ A, const u16* __restrict__ Bt,
    const float* __restrict__ bias, float* __restrict__ C, int N) {
    constexpr int K = 1024;
    __shared__ u16 Asl[2][128 * 32];
    __shared__ u16 Bsl[2][128 * 32];
    const int tid  = threadIdx.x;
    const int wave = tid >> 6, lane = tid & 63;
    const int wm = (wave & 1) * 64, wn = (wave >> 1) * 64;
    const int bm = blockIdx.y * 128, bn = blockIdx.x * 128;
    const int l15 = lane & 15, quad = lane >> 4;

    f32x4 acc[4][4];
#pragma unroll
    for (int i = 0; i < 4; i++)
#pragma unroll
        for (int j = 0; j < 4; j++) acc[i][j] = {0.f, 0.f, 0.f, 0.f};

    GEMM_KLOOP(A, Bt, bm, bn)

#pragma unroll
    for (int mi = 0; mi < 4; mi++) {
#pragma unroll
        for (int nj = 0; nj < 4; nj++) {
            int col = bn + wn + nj * 16 + l15;
            float bcol = bias[col];
#pragma unroll
            for (int r = 0; r < 4; r++) {
                int row = bm + wm + mi * 16 + quad * 4 + r;
                C[(size_t)row * N + col] = acc[mi][nj][r] + bcol;
            }
        }
    }
}

// ---------------------------------------------------------------------------
// kv partials from bf16 head-major k,v: grid (64 bn, NCH).
__global__ __launch_bounds__(256) void kv_part_kernel(
    const u16* __restrict__ kb, const u16* __restrict__ vb,
    float* __restrict__ kvpart, float* __restrict__ kspart) {
    int bn = blockIdx.x;
    const int rows = S_ / NCH;              // 128
    int s0 = blockIdx.y * rows;
    int tid = threadIdx.x;
    int ti = tid >> 4, tj = tid & 15;
    __shared__ float ks[16][64], vs[16][64];
    float acc[4][4] = {};
    float ksacc = 0.f;
    const u16* kbase = kb + (size_t)bn * (S_ * 64) + (size_t)s0 * 64;
    const u16* vbase = vb + (size_t)bn * (S_ * 64) + (size_t)s0 * 64;
    for (int ss = 0; ss < rows; ss += 16) {
        {
            int half = tid >> 7;
            int c = tid & 127;
            int rr = c >> 3, col = (c & 7) * 8;
            const u16* src = (half ? vbase : kbase) + (size_t)(ss + rr) * 64 + col;
            uint4 raw = *(const uint4*)src;
            float* dst = half ? &vs[rr][col] : &ks[rr][col];
            dst[0] = bfl(raw.x); dst[1] = bfh(raw.x);
            dst[2] = bfl(raw.y); dst[3] = bfh(raw.y);
            dst[4] = bfl(raw.z); dst[5] = bfh(raw.z);
            dst[6] = bfl(raw.w); dst[7] = bfh(raw.w);
        }
        __syncthreads();
#pragma unroll
        for (int r = 0; r < 16; r++) {
            float a[4], bb[4];
#pragma unroll
            for (int i = 0; i < 4; i++) a[i] = ks[r][ti * 4 + i];
#pragma unroll
            for (int j = 0; j < 4; j++) bb[j] = vs[r][tj * 4 + j];
#pragma unroll
            for (int i = 0; i < 4; i++)
#pragma unroll
                for (int j = 0; j < 4; j++)
                    acc[i][j] = fmaf(a[i], bb[j], acc[i][j]);
        }
        if (tid < 64) {
#pragma unroll
            for (int r = 0; r < 16; r++) ksacc += ks[r][tid];
        }
        __syncthreads();
    }
    size_t obase = ((size_t)blockIdx.y * 64 + bn) * 4096;
#pragma unroll
    for (int i = 0; i < 4; i++)
#pragma unroll
        for (int j = 0; j < 4; j++)
            kvpart[obase + (size_t)(ti * 4 + i) * 64 + tj * 4 + j] = acc[i][j];
    if (tid < 64)
        kspart[((size_t)blockIdx.y * 64 + bn) * 64 + tid] = ksacc;
}

// sum NCH partials for kv (262144) and ksum (4096) in one launch
__global__ __launch_bounds__(256) void reduce_part_kernel(
    const float* __restrict__ kvpart, const float* __restrict__ kspart,
    float* __restrict__ kvb, float* __restrict__ ksum) {
    int i = blockIdx.x * 256 + threadIdx.x;
    if (i < 262144) {
        float s = 0.f;
#pragma unroll
        for (int c = 0; c < NCH; c++) s += kvpart[(size_t)c * 262144 + i];
        kvb[i] = s;
    } else if (i < 262144 + 4096) {
        int j = i - 262144;
        float s = 0.f;
#pragma unroll
        for (int c = 0; c < NCH; c++) s += kspart[(size_t)c * 4096 + j];
        ksum[j] = s;
    }
}

// ---------------------------------------------------------------------------
// MFMA combine: per (b,n), num = Q[256x64] @ kv[64x64], den via ksum column.
__global__ __launch_bounds__(256) void combine_kernel(
    const u16* __restrict__ qb, const float* __restrict__ kvb,
    const float* __restrict__ ksum, const float* __restrict__ g,
    const float* __restrict__ coeffp, u16* __restrict__ cmb) {
    int bn = blockIdx.x;
    int b = bn >> 4, n = bn & 15;
    __shared__ u16 qs[256 * 72];
    __shared__ u16 kvT[64 * 72];
    __shared__ u16 ksl[128];
    int tid = threadIdx.x;
    int s0 = blockIdx.y * 256;

    const u16* qsrc = qb + (size_t)bn * (S_ * 64) + (size_t)s0 * 64;
    for (int c = tid; c < 2048; c += 256) {
        int t = c >> 3, k8 = (c & 7) * 8;
        float4 tmp = *(const float4*)(qsrc + (size_t)c * 8);
        *(float4*)&qs[t * 72 + k8] = tmp;
    }
    for (int c = tid; c < 1024; c += 256) {
        int i = c >> 4, d4 = (c & 15) * 4;
        float4 kvv = *(const float4*)&kvb[(size_t)bn * 4096 + i * 64 + d4];
        kvT[(d4 + 0) * 72 + i] = f2bf(kvv.x);
        kvT[(d4 + 1) * 72 + i] = f2bf(kvv.y);
        kvT[(d4 + 2) * 72 + i] = f2bf(kvv.z);
        kvT[(d4 + 3) * 72 + i] = f2bf(kvv.w);
    }
    if (tid < 64)        ksl[tid] = f2bf(ksum[bn * 64 + tid]);
    else if (tid < 128)  ksl[tid] = 0;
    __syncthreads();

    int wave = tid >> 6, lane = tid & 63;
    int l15 = lane & 15, quad = lane >> 4;
    int wt = wave * 64;

    int ko0 = (l15 == 0) ? quad * 8      : 64;
    int ko1 = (l15 == 0) ? 32 + quad * 8 : 64;
    bf16x8 ksf0 = *(const bf16x8*)&ksl[ko0];
    bf16x8 ksf1 = *(const bf16x8*)&ksl[ko1];

    bf16x8 bfr0[4], bfr1[4];
#pragma unroll
    for (int nj = 0; nj < 4; nj++) {
        bfr0[nj] = *(const bf16x8*)&kvT[(nj * 16 + l15) * 72 + quad * 8];
        bfr1[nj] = *(const bf16x8*)&kvT[(nj * 16 + l15) * 72 + 32 + quad * 8];
    }

    f32x4 acc[4][4], dacc[4];
#pragma unroll
    for (int i = 0; i < 4; i++) {
        dacc[i] = {0.f, 0.f, 0.f, 0.f};
#pragma unroll
        for (int j = 0; j < 4; j++) acc[i][j] = {0.f, 0.f, 0.f, 0.f};
    }

#pragma unroll
    for (int mi = 0; mi < 4; mi++) {
        bf16x8 a0 = *(const bf16x8*)&qs[(wt + mi * 16 + l15) * 72 + quad * 8];
        bf16x8 a1 = *(const bf16x8*)&qs[(wt + mi * 16 + l15) * 72 + 32 + quad * 8];
        dacc[mi] = __builtin_amdgcn_mfma_f32_16x16x32_bf16(a0, ksf0, dacc[mi], 0, 0, 0);
        dacc[mi] = __builtin_amdgcn_mfma_f32_16x16x32_bf16(a1, ksf1, dacc[mi], 0, 0, 0);
#pragma unroll
        for (int nj = 0; nj < 4; nj++) {
            acc[mi][nj] = __builtin_amdgcn_mfma_f32_16x16x32_bf16(
                a0, bfr0[nj], acc[mi][nj], 0, 0, 0);
            acc[mi][nj] = __builtin_amdgcn_mfma_f32_16x16x32_bf16(
                a1, bfr1[nj], acc[mi][nj], 0, 0, 0);
        }
    }

    float coeff = *coeffp;
#pragma unroll
    for (int mi = 0; mi < 4; mi++) {
#pragma unroll
        for (int r = 0; r < 4; r++) {
            int s = s0 + wt + mi * 16 + quad * 4 + r;
            int t = b * S_ + s;
            float den = __shfl(dacc[mi][r], lane & 48) + 1e-6f;
            float gv = g[t];
            float w1 = gv / den + (1.f - gv) * coeff;
#pragma unroll
            for (int nj = 0; nj < 4; nj++) {
                int d = nj * 16 + l15;
                cmb[(size_t)t * H_ + n * 64 + d] = f2bf(acc[mi][nj][r] * w1);
            }
        }
    }
}

// ---------------------------------------------------------------------------
extern "C" void kernel_launch(void* const* d_in, const int* in_sizes, int n_in,
                              void* d_out, int out_size, void* d_ws, size_t ws_size,
                              hipStream_t stream) {
    const float* hs    = (const float*)d_in[0];
    const float* mask  = (const float*)d_in[1];
    const float* Wq    = (const float*)d_in[2];
    const float* bq    = (const float*)d_in[3];
    const float* Wk    = (const float*)d_in[4];
    const float* bk    = (const float*)d_in[5];
    const float* Wv    = (const float*)d_in[6];
    const float* bv    = (const float*)d_in[7];
    const float* Wo    = (const float*)d_in[8];
    const float* bo    = (const float*)d_in[9];
    const float* Wg    = (const float*)d_in[10];
    const float* bg    = (const float*)d_in[11];
    const float* decay = (const float*)d_in[12];
    const float* gate  = (const float*)d_in[13];
    float* out = (float*)d_out;

    // ---- workspace layout
    float* ws     = (float*)d_ws;
    float* kvb    = ws;                         // 262144
    float* ksum   = kvb + 262144;               // 4096
    float* gbuf   = ksum + 4096;                // 8192
    float* coeff  = gbuf + 8192;                // 64
    float* cosT   = coeff + 64;                 // 65536
    float* sinT   = cosT + 65536;               // 65536
    float* bqkv   = sinT + 65536;               // 3072 (+pad to 4096)
    float* kspart = bqkv + 4096;                // NCH*4096 = 65536
    float* kvpart = kspart + 65536;             // NCH*262144 = 4194304
    u16*   hsb    = (u16*)(kvpart + 4194304);   // T*1024
    u16*   Wt     = hsb + (size_t)T_ * H_;      // 4096*1024
    u16*   WoT    = Wt + (size_t)3072 * H_;
    u16*   qb     = Wt + (size_t)4096 * H_;     // T*1024 head-major
    u16*   kb     = qb + (size_t)T_ * H_;
    u16*   vb     = kb + (size_t)T_ * H_;
    u16*   cmb    = vb + (size_t)T_ * H_;

    prep_kernel<<<(S_ * 32 + 3072 + 256) / 256 + 1, 256, 0, stream>>>(
        decay, gate, coeff, cosT, sinT, bq, bk, bv, bqkv);
    cvt_gate_kernel<<<T_, 256, 0, stream>>>(hs, Wg, bg, hsb, gbuf);
    pack_w_kernel<<<dim3(16, 16, 4), 256, 0, stream>>>(Wq, Wk, Wv, Wo, Wt);

    gemm_qkv_kernel<<<dim3(3072 / 128, T_ / 128), 256, 0, stream>>>(
        hsb, Wt, bqkv, mask, cosT, sinT, qb, kb, vb);

    kv_part_kernel<<<dim3(B_ * NH, NCH), 256, 0, stream>>>(
        kb, vb, kvpart, kspart);
    reduce_part_kernel<<<(262144 + 4096 + 255) / 256, 256, 0, stream>>>(
        kvpart, kspart, kvb, ksum);

    combine_kernel<<<dim3(B_ * NH, S_ / 256), 256, 0, stream>>>(
        qb, kvb, ksum, gbuf, coeff, cmb);

    gemm_out_kernel<<<dim3(H_ / 128, T_ / 128), 256, 0, stream>>>(
        cmb, WoT, bo, out, H_);
}